// Round 22
// baseline (333.542 us; speedup 1.0000x reference)
//
#include <hip/hip_runtime.h>

#define N_PIX   (32 * 64 * 64)          // 131072 pixel rows
#define E_DIM   64
#define N_E     1024
#define Z_ELEMS (N_PIX * E_DIM)         // 8388608

#define LOSS_OFF 0
#define ZQ_OFF   1
#define PERP_OFF (1 + Z_ELEMS)                          // 8388609
#define ENC_OFF  ((size_t)(2 + Z_ELEMS))                // 8388610
#define IDX_OFF  (ENC_OFF + (size_t)N_PIX * N_E)        // 142606338

// workspace layout (~4.3 MB)
#define WS_COUNTS   0          // u32[1024]
#define WS_LOSS     4096       // double
#define WS_EE       8192       // f32[1024]
#define WS_EMB16    12288      // bf16[1024*64] = 128 KB
#define WS_CAND     143360     // u32[4096*256] = 4 MB
#define WS_WCOUNT   4337664    // u32[4096]
#define NWAVES      4096       // 1024 blocks x 4 waves; segment == scan-wave
#define WAVE_CAP    256        // slots per wave (expected ~83)
#define MARGIN      4e-3f      // ~5x rigorous bf16-dot error bound

typedef float f32x2 __attribute__((ext_vector_type(2)));
typedef float f32x4 __attribute__((ext_vector_type(4)));
typedef short bf16x8 __attribute__((ext_vector_type(8)));   // 8 bf16 (4 VGPRs)
typedef unsigned long long u64;
typedef unsigned short ushort;

__device__ __forceinline__ float dpp_add_xor1(float v) {
    int i = __builtin_bit_cast(int, v);
    i = __builtin_amdgcn_mov_dpp(i, 0xB1, 0xF, 0xF, true);  // quad_perm(1,0,3,2)
    return v + __builtin_bit_cast(float, i);
}
__device__ __forceinline__ float dpp_add_xor2(float v) {
    int i = __builtin_bit_cast(int, v);
    i = __builtin_amdgcn_mov_dpp(i, 0x4E, 0xF, 0xF, true);  // quad_perm(2,3,0,1)
    return v + __builtin_bit_cast(float, i);
}
__device__ __forceinline__ ushort rne_bf16(float f) {       // round-nearest-even
    unsigned u = __builtin_bit_cast(unsigned, f);
    return (ushort)((u + 0x7FFFu + ((u >> 16) & 1u)) >> 16);
}

// ---- prep: ||e||^2 + bf16 codebook + counts/loss zeroing (R21, passed) ----
__global__ void vq_prep(const float* __restrict__ emb, float* __restrict__ ee,
                        ushort* __restrict__ emb16, unsigned* __restrict__ counts,
                        double* __restrict__ loss_acc) {
    int e = blockIdx.x * blockDim.x + threadIdx.x;
    if (e < N_E) {
        counts[e] = 0u;
        if (e == 0) *loss_acc = 0.0;
        const float* r = emb + e * E_DIM;
        float s0 = 0.f, s1 = 0.f, s2 = 0.f, s3 = 0.f;
        #pragma unroll
        for (int c = 0; c < E_DIM; c += 4) {
            s0 = fmaf(r[c],     r[c],     s0);
            s1 = fmaf(r[c + 1], r[c + 1], s1);
            s2 = fmaf(r[c + 2], r[c + 2], s2);
            s3 = fmaf(r[c + 3], r[c + 3], s3);
        }
        ee[e] = (s0 + s1) + (s2 + s3);
        #pragma unroll
        for (int j = 0; j < 64; j += 8) {
            bf16x8 v;
            #pragma unroll
            for (int q = 0; q < 8; ++q) v[q] = (short)rne_bf16(r[j + q]);
            *(bf16x8*)(emb16 + e * E_DIM + j) = v;
        }
    }
}

// A-fragment loader (passed R14/R16/R17, verbatim)
__device__ __forceinline__ bf16x8 load_afrag(const float* __restrict__ z,
                                             int px16, int lane, int khalf) {
    const int px = px16 + (lane & 15);
    const int b  = px >> 12;
    const int hw = px & 4095;
    const int c0 = khalf * 32 + ((lane >> 4) << 3);
    const float* zp = z + ((size_t)(b * E_DIM + c0)) * 4096 + hw;
    bf16x8 v;
    #pragma unroll
    for (int j = 0; j < 8; ++j) v[j] = (short)rne_bf16(zp[(size_t)j * 4096]);
    return v;
}

// ---- scan (R21 minus zero-fill: one-hot zeros now come from hipMemsetAsync,
// which sustains 6.7+ TB/s vs ~3-4 TB/s for the in-kernel NT stream) ----
__global__ __launch_bounds__(256, 4) void vq_scan(
    const float* __restrict__ z, const ushort* __restrict__ emb16,
    const float* __restrict__ ee,
    unsigned* __restrict__ cand, unsigned* __restrict__ wcount)
{
    const int tid  = threadIdx.x;
    const int lane = tid & 63;
    const int pxb  = blockIdx.x * 128 + (tid >> 6) * 32;   // wave: 32 px (2 tiles)

    bf16x8 afr[2][2];
    #pragma unroll
    for (int t = 0; t < 2; ++t)
        #pragma unroll
        for (int h = 0; h < 2; ++h)
            afr[t][h] = load_afrag(z, pxb + t * 16, lane, h);

    float m[2][4];
    #pragma unroll
    for (int t = 0; t < 2; ++t)
        #pragma unroll
        for (int r = 0; r < 4; ++r) m[t][r] = 3.4e38f;

    const int col = lane & 15;
    const int bko = ((lane >> 4) << 3);

    // ---- loop 1: per-lane min of approx d ----
    for (int cg = 0; cg < 64; ++cg) {
        const float eev = ee[cg * 16 + col];
        const ushort* br = emb16 + (cg * 16 + col) * E_DIM + bko;
        const bf16x8 b0 = *(const bf16x8*)br;
        const bf16x8 b1 = *(const bf16x8*)(br + 32);
        #pragma unroll
        for (int t = 0; t < 2; ++t) {
            f32x4 acc = {0.f, 0.f, 0.f, 0.f};
            acc = __builtin_amdgcn_mfma_f32_16x16x32_bf16(afr[t][0], b0, acc, 0, 0, 0);
            acc = __builtin_amdgcn_mfma_f32_16x16x32_bf16(afr[t][1], b1, acc, 0, 0, 0);
            #pragma unroll
            for (int r = 0; r < 4; ++r)
                m[t][r] = fminf(m[t][r], fmaf(-2.f, acc[r], eev));
        }
    }

    // ---- per-pixel limit (butterfly min across 16 code-columns; all lanes) ----
    float lim[2][4];
    #pragma unroll
    for (int t = 0; t < 2; ++t)
        #pragma unroll
        for (int r = 0; r < 4; ++r) {
            float v = m[t][r];
            v = fminf(v, __shfl_xor(v, 1));
            v = fminf(v, __shfl_xor(v, 2));
            v = fminf(v, __shfl_xor(v, 4));
            v = fminf(v, __shfl_xor(v, 8));
            lim[t][r] = v + MARGIN;
        }

    // ---- loop 2: rescan + ballot-aggregated emission ----
    const unsigned wid  = blockIdx.x * 4 + (tid >> 6);
    unsigned* wseg = cand + (size_t)wid * WAVE_CAP;
    const u64 below = (lane == 0) ? 0ull : ((~0ull) >> (64 - lane));
    unsigned wbase = 0;

    for (int cg = 0; cg < 64; ++cg) {
        const float eev = ee[cg * 16 + col];
        const ushort* br = emb16 + (cg * 16 + col) * E_DIM + bko;
        const bf16x8 b0 = *(const bf16x8*)br;
        const bf16x8 b1 = *(const bf16x8*)(br + 32);
        #pragma unroll
        for (int t = 0; t < 2; ++t) {
            f32x4 acc = {0.f, 0.f, 0.f, 0.f};
            acc = __builtin_amdgcn_mfma_f32_16x16x32_bf16(afr[t][0], b0, acc, 0, 0, 0);
            acc = __builtin_amdgcn_mfma_f32_16x16x32_bf16(afr[t][1], b1, acc, 0, 0, 0);
            #pragma unroll
            for (int r = 0; r < 4; ++r) {
                const float d = fmaf(-2.f, acc[r], eev);
                const bool hit = (d <= lim[t][r]);
                const u64 mask = __ballot(hit);
                if (hit) {
                    const unsigned pos = wbase + (unsigned)__popcll(mask & below);
                    if (pos < WAVE_CAP) {
                        const unsigned px = pxb + t * 16 + ((lane >> 4) << 2) + r;
                        wseg[pos] = (px << 10) | (unsigned)(cg * 16 + col);
                    }
                }
                wbase += (unsigned)__popcll(mask);
            }
        }
    }

    if (lane == 0) wcount[wid] = (wbase < WAVE_CAP) ? wbase : WAVE_CAP;
}

// ---- finish (R21, passed, verbatim): cleanup+resolve merged, LDS lkey ----
__global__ __launch_bounds__(256, 4) void vq_finish(
    const float* __restrict__ z, const float* __restrict__ emb,
    const float* __restrict__ ee, const unsigned* __restrict__ cand,
    const unsigned* __restrict__ wcount, float* __restrict__ out,
    unsigned* __restrict__ counts, double* __restrict__ loss_acc)
{
    __shared__ u64 lkey[32];

    const unsigned w = blockIdx.x;
    const int pxb = (int)(w * 32);
    const int tid = threadIdx.x;
    const int s = tid & 3;
    const unsigned quad = tid >> 2;         // 0..63

    if (tid < 32) lkey[tid] = ~0ull;
    __syncthreads();

    // ---- phase 1: entry-parallel exact eval (frozen tree) ----
    const unsigned n = wcount[w];
    const unsigned* seg = cand + (size_t)w * WAVE_CAP;
    for (unsigned j = quad; j < n; j += 64) {
        const unsigned ent = seg[j];
        const int p = ent >> 10, k = ent & 1023;
        const int b = p >> 12, hw = p & 4095;

        const float* zp = z + ((size_t)(b * E_DIM + s * 16)) * 4096 + hw;
        f32x4 zv[4];
        #pragma unroll
        for (int m = 0; m < 4; ++m)
            #pragma unroll
            for (int qi = 0; qi < 4; ++qi)
                zv[m][qi] = zp[(size_t)(4 * m + qi) * 4096];

        f32x4 za = {0.f,0.f,0.f,0.f};
        #pragma unroll
        for (int j2 = 0; j2 < 4; ++j2) za = __builtin_elementwise_fma(zv[j2], zv[j2], za);
        f32x2 zt = __builtin_shufflevector(za, za, 0, 1)
                 + __builtin_shufflevector(za, za, 2, 3);
        const float zz = dpp_add_xor2(dpp_add_xor1(zt.x + zt.y));

        const f32x4* rp = (const f32x4*)(emb + k * E_DIM) + s * 4;
        f32x4 a = {0.f,0.f,0.f,0.f};
        #pragma unroll
        for (int j2 = 0; j2 < 4; ++j2) a = __builtin_elementwise_fma(zv[j2], rp[j2], a);
        f32x2 t2 = __builtin_shufflevector(a, a, 0, 1)
                 + __builtin_shufflevector(a, a, 2, 3);
        const float dot = dpp_add_xor2(dpp_add_xor1(t2.x + t2.y));
        const float d = zz + ee[k] - 2.0f * dot;      // frozen exact form

        if (s == 0) {
            const u64 key = ((u64)__builtin_bit_cast(unsigned, d) << 32) | (unsigned)k;
            atomicMin(&lkey[p - pxb], key);           // d>0: bits order == fp order
        }
    }
    __syncthreads();

    // ---- phase 2: resolve body (verbatim layout), threads 0..31 ----
    if (tid < 32) {
        const int p  = pxb + tid;
        const int b  = p >> 12;
        const int hw = p & 4095;
        const int idx = (int)(unsigned)(lkey[tid] & 0xFFFFFFFFu);

        out[IDX_OFF + p] = (float)idx;
        out[ENC_OFF + (size_t)p * N_E + idx] = 1.0f;   // zeros via memset
        atomicAdd(&counts[idx], 1u);

        const f32x4* eb = (const f32x4*)(emb + idx * E_DIM);
        const float* zp = z + (size_t)b * E_DIM * 4096 + hw;
        float* zqp = out + ZQ_OFF + (size_t)b * E_DIM * 4096 + hw;
        f32x4 la = {0.f,0.f,0.f,0.f};
        #pragma unroll
        for (int m = 0; m < 16; ++m) {
            const f32x4 q = eb[m];
            f32x4 zq4;
            #pragma unroll
            for (int qi = 0; qi < 4; ++qi) {
                zq4[qi] = zp[(size_t)(4 * m + qi) * 4096];
                __builtin_nontemporal_store(q[qi], &zqp[(size_t)(4 * m + qi) * 4096]);
            }
            const f32x4 dq = q - zq4;
            la = __builtin_elementwise_fma(dq, dq, la);
        }
        float lsum = (la[0] + la[2]) + (la[1] + la[3]);
        #pragma unroll
        for (int o = 16; o > 0; o >>= 1) lsum += __shfl_down(lsum, o);
        if (tid == 0) atomicAdd(loss_acc, (double)lsum);
    }
}

// ---- finalize (verbatim) ----
__global__ void vq_final(const unsigned* __restrict__ counts,
                         const double* __restrict__ loss_acc,
                         float* __restrict__ out)
{
    __shared__ float red[N_E];
    const int e = threadIdx.x;
    const float em = (float)counts[e] * (1.0f / (float)N_PIX);
    red[e] = em * logf(em + 1e-10f);
    __syncthreads();
    for (int s = 512; s > 0; s >>= 1) {
        if (e < s) red[e] += red[e + s];
        __syncthreads();
    }
    if (e == 0) {
        out[PERP_OFF] = expf(-red[0]);
        out[LOSS_OFF] = (float)((*loss_acc) * (1.25 / (double)Z_ELEMS));
    }
}

extern "C" void kernel_launch(void* const* d_in, const int* in_sizes, int n_in,
                              void* d_out, int out_size, void* d_ws, size_t ws_size,
                              hipStream_t stream) {
    const float* z   = (const float*)d_in[0];
    const float* emb = (const float*)d_in[1];
    float* out = (float*)d_out;
    char* ws = (char*)d_ws;

    unsigned* counts   = (unsigned*)(ws + WS_COUNTS);
    double*   loss_acc = (double*)(ws + WS_LOSS);
    float*    ee       = (float*)(ws + WS_EE);
    ushort*   emb16    = (ushort*)(ws + WS_EMB16);
    unsigned* cand     = (unsigned*)(ws + WS_CAND);
    unsigned* wcount   = (unsigned*)(ws + WS_WCOUNT);

    // one-hot zeros via runtime fill (6.7+ TB/s, vs ~3-4 TB/s in-kernel NT)
    (void)hipMemsetAsync(out + ENC_OFF, 0, (size_t)N_PIX * N_E * 4, stream);
    vq_prep<<<4, 256, 0, stream>>>(emb, ee, emb16, counts, loss_acc);
    vq_scan<<<N_PIX / 128, 256, 0, stream>>>(z, emb16, ee, cand, wcount);
    vq_finish<<<NWAVES, 256, 0, stream>>>(z, emb, ee, cand, wcount, out,
                                          counts, loss_acc);
    vq_final<<<1, N_E, 0, stream>>>(counts, loss_acc, out);
}

// Round 23
// 228.981 us; speedup vs baseline: 1.4566x; 1.4566x over previous
//
#include <hip/hip_runtime.h>

#define N_PIX   (32 * 64 * 64)          // 131072 pixel rows
#define E_DIM   64
#define N_E     1024
#define Z_ELEMS (N_PIX * E_DIM)         // 8388608

#define LOSS_OFF 0
#define ZQ_OFF   1
#define PERP_OFF (1 + Z_ELEMS)                          // 8388609
#define ENC_OFF  ((size_t)(2 + Z_ELEMS))                // 8388610
#define IDX_OFF  (ENC_OFF + (size_t)N_PIX * N_E)        // 142606338

// workspace layout (~4.3 MB)
#define WS_COUNTS   0          // u32[1024]
#define WS_LOSS     4096       // double
#define WS_EE       8192       // f32[1024]
#define WS_EMB16    12288      // bf16[1024*64] = 128 KB
#define WS_CAND     143360     // u32[4096*256] = 4 MB
#define WS_WCOUNT   4337664    // u32[4096]
#define NWAVES      4096       // 1024 blocks x 4 waves; segment == scan-wave
#define WAVE_CAP    256        // slots per wave (expected ~83)
#define MARGIN      4e-3f      // ~5x rigorous bf16-dot error bound

typedef float f32x2 __attribute__((ext_vector_type(2)));
typedef float f32x4 __attribute__((ext_vector_type(4)));
typedef short bf16x8 __attribute__((ext_vector_type(8)));   // 8 bf16 (4 VGPRs)
typedef unsigned long long u64;
typedef unsigned short ushort;

__device__ __forceinline__ float dpp_add_xor1(float v) {
    int i = __builtin_bit_cast(int, v);
    i = __builtin_amdgcn_mov_dpp(i, 0xB1, 0xF, 0xF, true);  // quad_perm(1,0,3,2)
    return v + __builtin_bit_cast(float, i);
}
__device__ __forceinline__ float dpp_add_xor2(float v) {
    int i = __builtin_bit_cast(int, v);
    i = __builtin_amdgcn_mov_dpp(i, 0x4E, 0xF, 0xF, true);  // quad_perm(2,3,0,1)
    return v + __builtin_bit_cast(float, i);
}
__device__ __forceinline__ ushort rne_bf16(float f) {       // round-nearest-even
    unsigned u = __builtin_bit_cast(unsigned, f);
    return (ushort)((u + 0x7FFFu + ((u >> 16) & 1u)) >> 16);
}

// One one-hot row (1024 floats at rowb, rowb%4==2): threads 0..254 write an
// ALIGNED f32x4; thread 255 covers head+tail. PLAIN stores (not NT): the
// harness fill hits 6.6+ TB/s with cached stores; NT measured ~3.5 TB/s
// effective (R19-R21). One-hot is write-once-read-never; L2 pollution is
// harmless (z+emb working set << 32 MB).
__device__ __forceinline__ void zero_row(float* rowb, int tid) {
    if (tid < 255) {
        const f32x4 z4 = {0.f, 0.f, 0.f, 0.f};
        *(f32x4*)(rowb + 2 + 4 * tid) = z4;
    } else {
        const f32x2 z2 = {0.f, 0.f};
        *(f32x2*)rowb = z2;
        *(f32x2*)(rowb + 1022) = z2;
    }
}

// ---- prep: ||e||^2 + bf16 codebook + counts/loss zeroing (R21, passed) ----
__global__ void vq_prep(const float* __restrict__ emb, float* __restrict__ ee,
                        ushort* __restrict__ emb16, unsigned* __restrict__ counts,
                        double* __restrict__ loss_acc) {
    int e = blockIdx.x * blockDim.x + threadIdx.x;
    if (e < N_E) {
        counts[e] = 0u;
        if (e == 0) *loss_acc = 0.0;
        const float* r = emb + e * E_DIM;
        float s0 = 0.f, s1 = 0.f, s2 = 0.f, s3 = 0.f;
        #pragma unroll
        for (int c = 0; c < E_DIM; c += 4) {
            s0 = fmaf(r[c],     r[c],     s0);
            s1 = fmaf(r[c + 1], r[c + 1], s1);
            s2 = fmaf(r[c + 2], r[c + 2], s2);
            s3 = fmaf(r[c + 3], r[c + 3], s3);
        }
        ee[e] = (s0 + s1) + (s2 + s3);
        #pragma unroll
        for (int j = 0; j < 64; j += 8) {
            bf16x8 v;
            #pragma unroll
            for (int q = 0; q < 8; ++q) v[q] = (short)rne_bf16(r[j + q]);
            *(bf16x8*)(emb16 + e * E_DIM + j) = v;
        }
    }
}

// A-fragment loader (passed R14/R16/R17, verbatim)
__device__ __forceinline__ bf16x8 load_afrag(const float* __restrict__ z,
                                             int px16, int lane, int khalf) {
    const int px = px16 + (lane & 15);
    const int b  = px >> 12;
    const int hw = px & 4095;
    const int c0 = khalf * 32 + ((lane >> 4) << 3);
    const float* zp = z + ((size_t)(b * E_DIM + c0)) * 4096 + hw;
    bf16x8 v;
    #pragma unroll
    for (int j = 0; j < 8; ++j) v[j] = (short)rne_bf16(zp[(size_t)j * 4096]);
    return v;
}

// ---- scan (R21, passed; ONLY zero_row's store flavor changed) ----
__global__ __launch_bounds__(256, 4) void vq_scan(
    const float* __restrict__ z, const ushort* __restrict__ emb16,
    const float* __restrict__ ee, float* __restrict__ out,
    unsigned* __restrict__ cand, unsigned* __restrict__ wcount)
{
    const int tid  = threadIdx.x;
    const int lane = tid & 63;
    const int pxb  = blockIdx.x * 128 + (tid >> 6) * 32;   // wave: 32 px (2 tiles)

    bf16x8 afr[2][2];
    #pragma unroll
    for (int t = 0; t < 2; ++t)
        #pragma unroll
        for (int h = 0; h < 2; ++h)
            afr[t][h] = load_afrag(z, pxb + t * 16, lane, h);

    float m[2][4];
    #pragma unroll
    for (int t = 0; t < 2; ++t)
        #pragma unroll
        for (int r = 0; r < 4; ++r) m[t][r] = 3.4e38f;

    const size_t zb = ENC_OFF + (size_t)blockIdx.x * 128 * N_E;
    const int col = lane & 15;
    const int bko = ((lane >> 4) << 3);

    // ---- loop 1: per-lane min of approx d + zero rows 0..63 ----
    for (int cg = 0; cg < 64; ++cg) {
        const float eev = ee[cg * 16 + col];
        const ushort* br = emb16 + (cg * 16 + col) * E_DIM + bko;
        const bf16x8 b0 = *(const bf16x8*)br;
        const bf16x8 b1 = *(const bf16x8*)(br + 32);
        #pragma unroll
        for (int t = 0; t < 2; ++t) {
            f32x4 acc = {0.f, 0.f, 0.f, 0.f};
            acc = __builtin_amdgcn_mfma_f32_16x16x32_bf16(afr[t][0], b0, acc, 0, 0, 0);
            acc = __builtin_amdgcn_mfma_f32_16x16x32_bf16(afr[t][1], b1, acc, 0, 0, 0);
            #pragma unroll
            for (int r = 0; r < 4; ++r)
                m[t][r] = fminf(m[t][r], fmaf(-2.f, acc[r], eev));
        }
        zero_row(out + zb + (size_t)cg * N_E, tid);
    }

    // ---- per-pixel limit (butterfly min across 16 code-columns; all lanes) ----
    float lim[2][4];
    #pragma unroll
    for (int t = 0; t < 2; ++t)
        #pragma unroll
        for (int r = 0; r < 4; ++r) {
            float v = m[t][r];
            v = fminf(v, __shfl_xor(v, 1));
            v = fminf(v, __shfl_xor(v, 2));
            v = fminf(v, __shfl_xor(v, 4));
            v = fminf(v, __shfl_xor(v, 8));
            lim[t][r] = v + MARGIN;
        }

    // ---- loop 2: rescan + ballot-aggregated emission + zero rows 64..127 ----
    const unsigned wid  = blockIdx.x * 4 + (tid >> 6);
    unsigned* wseg = cand + (size_t)wid * WAVE_CAP;
    const u64 below = (lane == 0) ? 0ull : ((~0ull) >> (64 - lane));
    unsigned wbase = 0;

    for (int cg = 0; cg < 64; ++cg) {
        const float eev = ee[cg * 16 + col];
        const ushort* br = emb16 + (cg * 16 + col) * E_DIM + bko;
        const bf16x8 b0 = *(const bf16x8*)br;
        const bf16x8 b1 = *(const bf16x8*)(br + 32);
        #pragma unroll
        for (int t = 0; t < 2; ++t) {
            f32x4 acc = {0.f, 0.f, 0.f, 0.f};
            acc = __builtin_amdgcn_mfma_f32_16x16x32_bf16(afr[t][0], b0, acc, 0, 0, 0);
            acc = __builtin_amdgcn_mfma_f32_16x16x32_bf16(afr[t][1], b1, acc, 0, 0, 0);
            #pragma unroll
            for (int r = 0; r < 4; ++r) {
                const float d = fmaf(-2.f, acc[r], eev);
                const bool hit = (d <= lim[t][r]);
                const u64 mask = __ballot(hit);
                if (hit) {
                    const unsigned pos = wbase + (unsigned)__popcll(mask & below);
                    if (pos < WAVE_CAP) {
                        const unsigned px = pxb + t * 16 + ((lane >> 4) << 2) + r;
                        wseg[pos] = (px << 10) | (unsigned)(cg * 16 + col);
                    }
                }
                wbase += (unsigned)__popcll(mask);
            }
        }
        zero_row(out + zb + (size_t)(64 + cg) * N_E, tid);
    }

    if (lane == 0) wcount[wid] = (wbase < WAVE_CAP) ? wbase : WAVE_CAP;
}

// ---- finish (R21, passed, verbatim): cleanup+resolve merged, LDS lkey ----
__global__ __launch_bounds__(256, 4) void vq_finish(
    const float* __restrict__ z, const float* __restrict__ emb,
    const float* __restrict__ ee, const unsigned* __restrict__ cand,
    const unsigned* __restrict__ wcount, float* __restrict__ out,
    unsigned* __restrict__ counts, double* __restrict__ loss_acc)
{
    __shared__ u64 lkey[32];

    const unsigned w = blockIdx.x;
    const int pxb = (int)(w * 32);
    const int tid = threadIdx.x;
    const int s = tid & 3;
    const unsigned quad = tid >> 2;         // 0..63

    if (tid < 32) lkey[tid] = ~0ull;
    __syncthreads();

    // ---- phase 1: entry-parallel exact eval (frozen tree) ----
    const unsigned n = wcount[w];
    const unsigned* seg = cand + (size_t)w * WAVE_CAP;
    for (unsigned j = quad; j < n; j += 64) {
        const unsigned ent = seg[j];
        const int p = ent >> 10, k = ent & 1023;
        const int b = p >> 12, hw = p & 4095;

        const float* zp = z + ((size_t)(b * E_DIM + s * 16)) * 4096 + hw;
        f32x4 zv[4];
        #pragma unroll
        for (int m = 0; m < 4; ++m)
            #pragma unroll
            for (int qi = 0; qi < 4; ++qi)
                zv[m][qi] = zp[(size_t)(4 * m + qi) * 4096];

        f32x4 za = {0.f,0.f,0.f,0.f};
        #pragma unroll
        for (int j2 = 0; j2 < 4; ++j2) za = __builtin_elementwise_fma(zv[j2], zv[j2], za);
        f32x2 zt = __builtin_shufflevector(za, za, 0, 1)
                 + __builtin_shufflevector(za, za, 2, 3);
        const float zz = dpp_add_xor2(dpp_add_xor1(zt.x + zt.y));

        const f32x4* rp = (const f32x4*)(emb + k * E_DIM) + s * 4;
        f32x4 a = {0.f,0.f,0.f,0.f};
        #pragma unroll
        for (int j2 = 0; j2 < 4; ++j2) a = __builtin_elementwise_fma(zv[j2], rp[j2], a);
        f32x2 t2 = __builtin_shufflevector(a, a, 0, 1)
                 + __builtin_shufflevector(a, a, 2, 3);
        const float dot = dpp_add_xor2(dpp_add_xor1(t2.x + t2.y));
        const float d = zz + ee[k] - 2.0f * dot;      // frozen exact form

        if (s == 0) {
            const u64 key = ((u64)__builtin_bit_cast(unsigned, d) << 32) | (unsigned)k;
            atomicMin(&lkey[p - pxb], key);           // d>0: bits order == fp order
        }
    }
    __syncthreads();

    // ---- phase 2: resolve body (verbatim layout), threads 0..31 ----
    if (tid < 32) {
        const int p  = pxb + tid;
        const int b  = p >> 12;
        const int hw = p & 4095;
        const int idx = (int)(unsigned)(lkey[tid] & 0xFFFFFFFFu);

        out[IDX_OFF + p] = (float)idx;
        out[ENC_OFF + (size_t)p * N_E + idx] = 1.0f;   // zeros streamed in scan
        atomicAdd(&counts[idx], 1u);

        const f32x4* eb = (const f32x4*)(emb + idx * E_DIM);
        const float* zp = z + (size_t)b * E_DIM * 4096 + hw;
        float* zqp = out + ZQ_OFF + (size_t)b * E_DIM * 4096 + hw;
        f32x4 la = {0.f,0.f,0.f,0.f};
        #pragma unroll
        for (int m = 0; m < 16; ++m) {
            const f32x4 q = eb[m];
            f32x4 zq4;
            #pragma unroll
            for (int qi = 0; qi < 4; ++qi) {
                zq4[qi] = zp[(size_t)(4 * m + qi) * 4096];
                __builtin_nontemporal_store(q[qi], &zqp[(size_t)(4 * m + qi) * 4096]);
            }
            const f32x4 dq = q - zq4;
            la = __builtin_elementwise_fma(dq, dq, la);
        }
        float lsum = (la[0] + la[2]) + (la[1] + la[3]);
        #pragma unroll
        for (int o = 16; o > 0; o >>= 1) lsum += __shfl_down(lsum, o);
        if (tid == 0) atomicAdd(loss_acc, (double)lsum);
    }
}

// ---- finalize (verbatim) ----
__global__ void vq_final(const unsigned* __restrict__ counts,
                         const double* __restrict__ loss_acc,
                         float* __restrict__ out)
{
    __shared__ float red[N_E];
    const int e = threadIdx.x;
    const float em = (float)counts[e] * (1.0f / (float)N_PIX);
    red[e] = em * logf(em + 1e-10f);
    __syncthreads();
    for (int s = 512; s > 0; s >>= 1) {
        if (e < s) red[e] += red[e + s];
        __syncthreads();
    }
    if (e == 0) {
        out[PERP_OFF] = expf(-red[0]);
        out[LOSS_OFF] = (float)((*loss_acc) * (1.25 / (double)Z_ELEMS));
    }
}

extern "C" void kernel_launch(void* const* d_in, const int* in_sizes, int n_in,
                              void* d_out, int out_size, void* d_ws, size_t ws_size,
                              hipStream_t stream) {
    const float* z   = (const float*)d_in[0];
    const float* emb = (const float*)d_in[1];
    float* out = (float*)d_out;
    char* ws = (char*)d_ws;

    unsigned* counts   = (unsigned*)(ws + WS_COUNTS);
    double*   loss_acc = (double*)(ws + WS_LOSS);
    float*    ee       = (float*)(ws + WS_EE);
    ushort*   emb16    = (ushort*)(ws + WS_EMB16);
    unsigned* cand     = (unsigned*)(ws + WS_CAND);
    unsigned* wcount   = (unsigned*)(ws + WS_WCOUNT);

    vq_prep<<<4, 256, 0, stream>>>(emb, ee, emb16, counts, loss_acc);
    vq_scan<<<N_PIX / 128, 256, 0, stream>>>(z, emb16, ee, out, cand, wcount);
    vq_finish<<<NWAVES, 256, 0, stream>>>(z, emb, ee, cand, wcount, out,
                                          counts, loss_acc);
    vq_final<<<1, N_E, 0, stream>>>(counts, loss_acc, out);
}

// Round 25
// 228.486 us; speedup vs baseline: 1.4598x; 1.0022x over previous
//
#include <hip/hip_runtime.h>

#define N_PIX   (32 * 64 * 64)          // 131072 pixel rows
#define E_DIM   64
#define N_E     1024
#define Z_ELEMS (N_PIX * E_DIM)         // 8388608

#define LOSS_OFF 0
#define ZQ_OFF   1
#define PERP_OFF (1 + Z_ELEMS)                          // 8388609
#define ENC_OFF  ((size_t)(2 + Z_ELEMS))                // 8388610
#define IDX_OFF  (ENC_OFF + (size_t)N_PIX * N_E)        // 142606338

// workspace layout (~4.3 MB)
#define WS_COUNTS   0          // u32[1024]
#define WS_LOSS     4096       // double
#define WS_EE       8192       // f32[1024]
#define WS_EMB16    12288      // bf16[1024*64] = 128 KB
#define WS_CAND     143360     // u32[4096*256] = 4 MB
#define WS_WCOUNT   4337664    // u32[4096]
#define NWAVES      4096       // 1024 blocks x 4 waves; segment == scan-wave
#define WAVE_CAP    256        // slots per wave (expected ~83)
#define MARGIN      4e-3f      // ~5x rigorous bf16-dot error bound

typedef float f32x2 __attribute__((ext_vector_type(2)));
typedef float f32x4 __attribute__((ext_vector_type(4)));
typedef short bf16x8 __attribute__((ext_vector_type(8)));   // 8 bf16 (4 VGPRs)
typedef unsigned long long u64;
typedef unsigned short ushort;

__device__ __forceinline__ float dpp_add_xor1(float v) {
    int i = __builtin_bit_cast(int, v);
    i = __builtin_amdgcn_mov_dpp(i, 0xB1, 0xF, 0xF, true);  // quad_perm(1,0,3,2)
    return v + __builtin_bit_cast(float, i);
}
__device__ __forceinline__ float dpp_add_xor2(float v) {
    int i = __builtin_bit_cast(int, v);
    i = __builtin_amdgcn_mov_dpp(i, 0x4E, 0xF, 0xF, true);  // quad_perm(2,3,0,1)
    return v + __builtin_bit_cast(float, i);
}
__device__ __forceinline__ ushort rne_bf16(float f) {       // round-nearest-even
    unsigned u = __builtin_bit_cast(unsigned, f);
    return (ushort)((u + 0x7FFFu + ((u >> 16) & 1u)) >> 16);
}

// One one-hot row (1024 floats at rowb, rowb%4==2): threads 0..254 write an
// ALIGNED f32x4; thread 255 covers head+tail. PLAIN stores (not NT): the
// harness fill hits 6.6+ TB/s with cached stores; NT measured ~3.5 TB/s
// effective (R19-R21). One-hot is write-once-read-never; L2 pollution is
// harmless (z+emb working set << 32 MB).
__device__ __forceinline__ void zero_row(float* rowb, int tid) {
    if (tid < 255) {
        const f32x4 z4 = {0.f, 0.f, 0.f, 0.f};
        *(f32x4*)(rowb + 2 + 4 * tid) = z4;
    } else {
        const f32x2 z2 = {0.f, 0.f};
        *(f32x2*)rowb = z2;
        *(f32x2*)(rowb + 1022) = z2;
    }
}

// ---- prep: ||e||^2 + bf16 codebook + counts/loss zeroing (R21, passed) ----
__global__ void vq_prep(const float* __restrict__ emb, float* __restrict__ ee,
                        ushort* __restrict__ emb16, unsigned* __restrict__ counts,
                        double* __restrict__ loss_acc) {
    int e = blockIdx.x * blockDim.x + threadIdx.x;
    if (e < N_E) {
        counts[e] = 0u;
        if (e == 0) *loss_acc = 0.0;
        const float* r = emb + e * E_DIM;
        float s0 = 0.f, s1 = 0.f, s2 = 0.f, s3 = 0.f;
        #pragma unroll
        for (int c = 0; c < E_DIM; c += 4) {
            s0 = fmaf(r[c],     r[c],     s0);
            s1 = fmaf(r[c + 1], r[c + 1], s1);
            s2 = fmaf(r[c + 2], r[c + 2], s2);
            s3 = fmaf(r[c + 3], r[c + 3], s3);
        }
        ee[e] = (s0 + s1) + (s2 + s3);
        #pragma unroll
        for (int j = 0; j < 64; j += 8) {
            bf16x8 v;
            #pragma unroll
            for (int q = 0; q < 8; ++q) v[q] = (short)rne_bf16(r[j + q]);
            *(bf16x8*)(emb16 + e * E_DIM + j) = v;
        }
    }
}

// A-fragment loader (passed R14/R16/R17, verbatim)
__device__ __forceinline__ bf16x8 load_afrag(const float* __restrict__ z,
                                             int px16, int lane, int khalf) {
    const int px = px16 + (lane & 15);
    const int b  = px >> 12;
    const int hw = px & 4095;
    const int c0 = khalf * 32 + ((lane >> 4) << 3);
    const float* zp = z + ((size_t)(b * E_DIM + c0)) * 4096 + hw;
    bf16x8 v;
    #pragma unroll
    for (int j = 0; j < 8; ++j) v[j] = (short)rne_bf16(zp[(size_t)j * 4096]);
    return v;
}

// ---- scan (R23, passed, verbatim) ----
__global__ __launch_bounds__(256, 4) void vq_scan(
    const float* __restrict__ z, const ushort* __restrict__ emb16,
    const float* __restrict__ ee, float* __restrict__ out,
    unsigned* __restrict__ cand, unsigned* __restrict__ wcount)
{
    const int tid  = threadIdx.x;
    const int lane = tid & 63;
    const int pxb  = blockIdx.x * 128 + (tid >> 6) * 32;   // wave: 32 px (2 tiles)

    bf16x8 afr[2][2];
    #pragma unroll
    for (int t = 0; t < 2; ++t)
        #pragma unroll
        for (int h = 0; h < 2; ++h)
            afr[t][h] = load_afrag(z, pxb + t * 16, lane, h);

    float m[2][4];
    #pragma unroll
    for (int t = 0; t < 2; ++t)
        #pragma unroll
        for (int r = 0; r < 4; ++r) m[t][r] = 3.4e38f;

    const size_t zb = ENC_OFF + (size_t)blockIdx.x * 128 * N_E;
    const int col = lane & 15;
    const int bko = ((lane >> 4) << 3);

    // ---- loop 1: per-lane min of approx d + zero rows 0..63 ----
    for (int cg = 0; cg < 64; ++cg) {
        const float eev = ee[cg * 16 + col];
        const ushort* br = emb16 + (cg * 16 + col) * E_DIM + bko;
        const bf16x8 b0 = *(const bf16x8*)br;
        const bf16x8 b1 = *(const bf16x8*)(br + 32);
        #pragma unroll
        for (int t = 0; t < 2; ++t) {
            f32x4 acc = {0.f, 0.f, 0.f, 0.f};
            acc = __builtin_amdgcn_mfma_f32_16x16x32_bf16(afr[t][0], b0, acc, 0, 0, 0);
            acc = __builtin_amdgcn_mfma_f32_16x16x32_bf16(afr[t][1], b1, acc, 0, 0, 0);
            #pragma unroll
            for (int r = 0; r < 4; ++r)
                m[t][r] = fminf(m[t][r], fmaf(-2.f, acc[r], eev));
        }
        zero_row(out + zb + (size_t)cg * N_E, tid);
    }

    // ---- per-pixel limit (butterfly min across 16 code-columns; all lanes) ----
    float lim[2][4];
    #pragma unroll
    for (int t = 0; t < 2; ++t)
        #pragma unroll
        for (int r = 0; r < 4; ++r) {
            float v = m[t][r];
            v = fminf(v, __shfl_xor(v, 1));
            v = fminf(v, __shfl_xor(v, 2));
            v = fminf(v, __shfl_xor(v, 4));
            v = fminf(v, __shfl_xor(v, 8));
            lim[t][r] = v + MARGIN;
        }

    // ---- loop 2: rescan + ballot-aggregated emission + zero rows 64..127 ----
    const unsigned wid  = blockIdx.x * 4 + (tid >> 6);
    unsigned* wseg = cand + (size_t)wid * WAVE_CAP;
    const u64 below = (lane == 0) ? 0ull : ((~0ull) >> (64 - lane));
    unsigned wbase = 0;

    for (int cg = 0; cg < 64; ++cg) {
        const float eev = ee[cg * 16 + col];
        const ushort* br = emb16 + (cg * 16 + col) * E_DIM + bko;
        const bf16x8 b0 = *(const bf16x8*)br;
        const bf16x8 b1 = *(const bf16x8*)(br + 32);
        #pragma unroll
        for (int t = 0; t < 2; ++t) {
            f32x4 acc = {0.f, 0.f, 0.f, 0.f};
            acc = __builtin_amdgcn_mfma_f32_16x16x32_bf16(afr[t][0], b0, acc, 0, 0, 0);
            acc = __builtin_amdgcn_mfma_f32_16x16x32_bf16(afr[t][1], b1, acc, 0, 0, 0);
            #pragma unroll
            for (int r = 0; r < 4; ++r) {
                const float d = fmaf(-2.f, acc[r], eev);
                const bool hit = (d <= lim[t][r]);
                const u64 mask = __ballot(hit);
                if (hit) {
                    const unsigned pos = wbase + (unsigned)__popcll(mask & below);
                    if (pos < WAVE_CAP) {
                        const unsigned px = pxb + t * 16 + ((lane >> 4) << 2) + r;
                        wseg[pos] = (px << 10) | (unsigned)(cg * 16 + col);
                    }
                }
                wbase += (unsigned)__popcll(mask);
            }
        }
        zero_row(out + zb + (size_t)(64 + cg) * N_E, tid);
    }

    if (lane == 0) wcount[wid] = (wbase < WAVE_CAP) ? wbase : WAVE_CAP;
}

// ---- finish (R21/R23, passed, verbatim): cleanup+resolve merged, LDS lkey ----
__global__ __launch_bounds__(256, 4) void vq_finish(
    const float* __restrict__ z, const float* __restrict__ emb,
    const float* __restrict__ ee, const unsigned* __restrict__ cand,
    const unsigned* __restrict__ wcount, float* __restrict__ out,
    unsigned* __restrict__ counts, double* __restrict__ loss_acc)
{
    __shared__ u64 lkey[32];

    const unsigned w = blockIdx.x;
    const int pxb = (int)(w * 32);
    const int tid = threadIdx.x;
    const int s = tid & 3;
    const unsigned quad = tid >> 2;         // 0..63

    if (tid < 32) lkey[tid] = ~0ull;
    __syncthreads();

    // ---- phase 1: entry-parallel exact eval (frozen tree) ----
    const unsigned n = wcount[w];
    const unsigned* seg = cand + (size_t)w * WAVE_CAP;
    for (unsigned j = quad; j < n; j += 64) {
        const unsigned ent = seg[j];
        const int p = ent >> 10, k = ent & 1023;
        const int b = p >> 12, hw = p & 4095;

        const float* zp = z + ((size_t)(b * E_DIM + s * 16)) * 4096 + hw;
        f32x4 zv[4];
        #pragma unroll
        for (int m = 0; m < 4; ++m)
            #pragma unroll
            for (int qi = 0; qi < 4; ++qi)
                zv[m][qi] = zp[(size_t)(4 * m + qi) * 4096];

        f32x4 za = {0.f,0.f,0.f,0.f};
        #pragma unroll
        for (int j2 = 0; j2 < 4; ++j2) za = __builtin_elementwise_fma(zv[j2], zv[j2], za);
        f32x2 zt = __builtin_shufflevector(za, za, 0, 1)
                 + __builtin_shufflevector(za, za, 2, 3);
        const float zz = dpp_add_xor2(dpp_add_xor1(zt.x + zt.y));

        const f32x4* rp = (const f32x4*)(emb + k * E_DIM) + s * 4;
        f32x4 a = {0.f,0.f,0.f,0.f};
        #pragma unroll
        for (int j2 = 0; j2 < 4; ++j2) a = __builtin_elementwise_fma(zv[j2], rp[j2], a);
        f32x2 t2 = __builtin_shufflevector(a, a, 0, 1)
                 + __builtin_shufflevector(a, a, 2, 3);
        const float dot = dpp_add_xor2(dpp_add_xor1(t2.x + t2.y));
        const float d = zz + ee[k] - 2.0f * dot;      // frozen exact form

        if (s == 0) {
            const u64 key = ((u64)__builtin_bit_cast(unsigned, d) << 32) | (unsigned)k;
            atomicMin(&lkey[p - pxb], key);           // d>0: bits order == fp order
        }
    }
    __syncthreads();

    // ---- phase 2: resolve body (verbatim layout), threads 0..31 ----
    if (tid < 32) {
        const int p  = pxb + tid;
        const int b  = p >> 12;
        const int hw = p & 4095;
        const int idx = (int)(unsigned)(lkey[tid] & 0xFFFFFFFFu);

        out[IDX_OFF + p] = (float)idx;
        out[ENC_OFF + (size_t)p * N_E + idx] = 1.0f;   // zeros streamed in scan
        atomicAdd(&counts[idx], 1u);

        const f32x4* eb = (const f32x4*)(emb + idx * E_DIM);
        const float* zp = z + (size_t)b * E_DIM * 4096 + hw;
        float* zqp = out + ZQ_OFF + (size_t)b * E_DIM * 4096 + hw;
        f32x4 la = {0.f,0.f,0.f,0.f};
        #pragma unroll
        for (int m = 0; m < 16; ++m) {
            const f32x4 q = eb[m];
            f32x4 zq4;
            #pragma unroll
            for (int qi = 0; qi < 4; ++qi) {
                zq4[qi] = zp[(size_t)(4 * m + qi) * 4096];
                __builtin_nontemporal_store(q[qi], &zqp[(size_t)(4 * m + qi) * 4096]);
            }
            const f32x4 dq = q - zq4;
            la = __builtin_elementwise_fma(dq, dq, la);
        }
        float lsum = (la[0] + la[2]) + (la[1] + la[3]);
        #pragma unroll
        for (int o = 16; o > 0; o >>= 1) lsum += __shfl_down(lsum, o);
        if (tid == 0) atomicAdd(loss_acc, (double)lsum);
    }
}

// ---- finalize (verbatim) ----
__global__ void vq_final(const unsigned* __restrict__ counts,
                         const double* __restrict__ loss_acc,
                         float* __restrict__ out)
{
    __shared__ float red[N_E];
    const int e = threadIdx.x;
    const float em = (float)counts[e] * (1.0f / (float)N_PIX);
    red[e] = em * logf(em + 1e-10f);
    __syncthreads();
    for (int s = 512; s > 0; s >>= 1) {
        if (e < s) red[e] += red[e + s];
        __syncthreads();
    }
    if (e == 0) {
        out[PERP_OFF] = expf(-red[0]);
        out[LOSS_OFF] = (float)((*loss_acc) * (1.25 / (double)Z_ELEMS));
    }
}

extern "C" void kernel_launch(void* const* d_in, const int* in_sizes, int n_in,
                              void* d_out, int out_size, void* d_ws, size_t ws_size,
                              hipStream_t stream) {
    const float* z   = (const float*)d_in[0];
    const float* emb = (const float*)d_in[1];
    float* out = (float*)d_out;
    char* ws = (char*)d_ws;

    unsigned* counts   = (unsigned*)(ws + WS_COUNTS);
    double*   loss_acc = (double*)(ws + WS_LOSS);
    float*    ee       = (float*)(ws + WS_EE);
    ushort*   emb16    = (ushort*)(ws + WS_EMB16);
    unsigned* cand     = (unsigned*)(ws + WS_CAND);
    unsigned* wcount   = (unsigned*)(ws + WS_WCOUNT);

    vq_prep<<<4, 256, 0, stream>>>(emb, ee, emb16, counts, loss_acc);
    vq_scan<<<N_PIX / 128, 256, 0, stream>>>(z, emb16, ee, out, cand, wcount);
    vq_finish<<<NWAVES, 256, 0, stream>>>(z, emb, ee, cand, wcount, out,
                                          counts, loss_acc);
    vq_final<<<1, N_E, 0, stream>>>(counts, loss_acc, out);
}